// Round 12
// baseline (2218.878 us; speedup 1.0000x reference)
//
#include <hip/hip_runtime.h>
#include <hip/hip_bf16.h>

#define KD 4096
#define ND 11008
#define MD 16384
#define KGD 32
#define NT (KD / 64)

typedef __hip_bfloat16 bf16;
typedef float f32x4 __attribute__((ext_vector_type(4)));
typedef short bf16x8 __attribute__((ext_vector_type(8)));
typedef unsigned int uint;

#define WAITV(n) asm volatile("s_waitcnt vmcnt(" #n ")" ::: "memory")
#define BAR()    asm volatile("s_barrier" ::: "memory")
#define LGKM0()  asm volatile("s_waitcnt lgkmcnt(0)" ::: "memory")

__device__ __forceinline__ void gload16(const bf16* g, bf16* l) {
    __builtin_amdgcn_global_load_lds((const __attribute__((address_space(1))) void*)g,
                                     (__attribute__((address_space(3))) void*)l, 16, 0, 0);
}

// ---------------------------------------------------------------------------
// x: fp32 -> bf16 (8 elems/thread)
// ---------------------------------------------------------------------------
__global__ void cvt_kernel(const float* __restrict__ x, bf16* __restrict__ y, int n8) {
    int i = blockIdx.x * blockDim.x + threadIdx.x;
    if (i >= n8) return;
    const f32x4* p = reinterpret_cast<const f32x4*>(x + (size_t)i * 8);
    f32x4 a = p[0], b = p[1];
    bf16 o[8];
#pragma unroll
    for (int e = 0; e < 4; ++e) {
        o[e]     = __float2bfloat16(a[e]);
        o[4 + e] = __float2bfloat16(b[e]);
    }
    *reinterpret_cast<bf16x8*>(y + (size_t)i * 8) = *reinterpret_cast<bf16x8*>(o);
}

// ---------------------------------------------------------------------------
// repack: reference stores ONE byte (2 nibbles) per int32 (N x K/2 int32,
// 90 MB). Compress to true-packed bytes (22.5 MB): byte j of row n covers
// k=2j (low nibble), k=2j+1 (high nibble). Thread i: 4 int32 -> 1 uint.
// ---------------------------------------------------------------------------
__global__ void repack_kernel(const int* __restrict__ wp, uint* __restrict__ wpk, int n4) {
    int i = blockIdx.x * blockDim.x + threadIdx.x;
    if (i >= n4) return;
    const int4 v = *reinterpret_cast<const int4*>(wp + (size_t)i * 4);
    wpk[i] = (uint)(v.x & 0xFF) | ((uint)(v.y & 0xFF) << 8) |
             ((uint)(v.z & 0xFF) << 16) | ((uint)(v.w & 0xFF) << 24);
}

// ---------------------------------------------------------------------------
// GEMM: C[M,N] = A[M,K] * Wdeq[N,K]^T, A bf16 (ws), W true-packed int4 (ws)
// + fp32 scales, fp32 out. 256x256 tile, BK=64 (two kh=32), 512 thr / 8
// waves (2M x 4N), per-wave out 128x64, mfma_f32_16x16x32_bf16, 128 KiB LDS
// double-buffered, proven conflict-free chunk swizzle. B staged from packed
// int4 (4x fewer bytes than bf16): per thread 2x dwordx2 + 1 scale ->
// VALU dequant -> 4x ds_write_b128 into the same swizzled layout as A.
// Each uint32 = 4 bytes = 8 k-values: uint index i = t*8 + kh*4 + chunk,
// byte b2 -> k = 64t + 32kh + 8*chunk + 2*b2 (+1 for high nibble).
// vmcnt ledger: 7 VMEM/tile (4 A-gload_lds + 2 B-dwordx2 + 1 scale);
// WAITV(7) drains exactly the previous tile's window (reg loads are
// additionally compiler-tracked). ds_writes visible via LGKM0 + BAR.
// ---------------------------------------------------------------------------
__global__ __launch_bounds__(512, 2) void gemm256(const bf16* __restrict__ A,
                                                  const uint* __restrict__ wpk,
                                                  const float* __restrict__ sc,
                                                  float* __restrict__ C,
                                                  int mtiles, int ntiles) {
    __shared__ bf16 lds[2][2][2][8192];  // [buf][kh][op(A=0/B=1)][256 x 32, swizzled]
    const int tid  = threadIdx.x;
    const int lane = tid & 63;
    const int w    = tid >> 6;

    // bijective XCD-aware block swizzle
    int nwg = mtiles * ntiles;
    int orig = blockIdx.x;
    int q8 = nwg >> 3, r8 = nwg & 7;
    int xcd = orig & 7, off = orig >> 3;
    int wg = (xcd < r8 ? xcd * (q8 + 1) : r8 * (q8 + 1) + (xcd - r8) * q8) + off;
    const int mb = wg / ntiles, nb = wg - mb * ntiles;
    const int m0 = mb * 256, n0 = nb * 256;

    const int wm = w >> 2, wn = w & 3;
    const int rl = lane & 15, kq = lane >> 4;
    const int sz = (rl >> 1) & 3;
    const int ro = 8 * (kq ^ sz);          // swizzled k-chunk for ds_read

    // A staging source (pre-swizzled so linear gload_lds dest == swizzled layout)
    const int src_c = (((lane & 3) ^ ((lane >> 3) & 3)) << 3);
    const int src_r = (w << 4) + (lane >> 2);
    const bf16* Abase = A + (size_t)(m0 + src_r) * KD + src_c;

    // B packed source: thread -> row rB, half hB (chunks 2hB, 2hB+1 of each kh)
    const int rB = tid >> 1, hB = tid & 1;
    const int qrB = (rB >> 1) & 3;
    const int baseB = rB * 32;             // elem offset within [kh] plane
    const uint*  wrow = wpk + (size_t)(n0 + rB) * (KD / 8);   // 512 uints/row
    const float* srow = sc + (size_t)(n0 + rB) * KGD;

    f32x4 acc[8][4] = {};

    auto stageA = [&](int b, int k0) {
#pragma unroll
        for (int kh = 0; kh < 2; ++kh) {
            const bf16* ga = Abase + k0 + kh * 32;
            bf16* la = &lds[b][kh][0][w * 512];
            gload16(ga, la);
            gload16(ga + (size_t)128 * KD, la + 4096);
        }
    };

    auto loadB = [&](int t, uint2& d0, uint2& d1, float& ss) {
        const uint* p = wrow + t * 8 + hB * 2;
        d0 = *reinterpret_cast<const uint2*>(p);       // kh0: chunks 2hB, 2hB+1
        d1 = *reinterpret_cast<const uint2*>(p + 4);   // kh1: chunks 2hB, 2hB+1
        ss = srow[t >> 1];                             // group = t/2 (BK=64, GS=128)
    };

    auto dqw = [&](int buf, uint2 d0, uint2 d1, float s) {
        const float ms8 = s * -8.0f;
#pragma unroll
        for (int kh = 0; kh < 2; ++kh) {
            uint v0 = kh ? d1.x : d0.x;
            uint v1 = kh ? d1.y : d0.y;
#pragma unroll
            for (int c = 0; c < 2; ++c) {
                uint u = c ? v1 : v0;
                int slot = ((2 * hB + c) ^ qrB);
                bf16 o[8];
#pragma unroll
                for (int b2 = 0; b2 < 4; ++b2) {
                    uint by = (u >> (8 * b2)) & 0xFFu;
                    o[2 * b2]     = __float2bfloat16(fmaf((float)(by & 0xFu), s, ms8));
                    o[2 * b2 + 1] = __float2bfloat16(fmaf((float)(by >> 4), s, ms8));
                }
                *reinterpret_cast<bf16x8*>(&lds[buf][kh][1][baseB + slot * 8]) =
                    *reinterpret_cast<bf16x8*>(o);
            }
        }
    };

    auto compute = [&](int b) {
#pragma unroll
        for (int kh = 0; kh < 2; ++kh) {
            bf16x8 af[8], bfr[4];
#pragma unroll
            for (int mi = 0; mi < 8; ++mi)
                af[mi] = *reinterpret_cast<const bf16x8*>(
                    &lds[b][kh][0][(wm * 128 + mi * 16 + rl) * 32 + ro]);
#pragma unroll
            for (int ni = 0; ni < 4; ++ni)
                bfr[ni] = *reinterpret_cast<const bf16x8*>(
                    &lds[b][kh][1][(wn * 64 + ni * 16 + rl) * 32 + ro]);
            __builtin_amdgcn_s_setprio(1);
#pragma unroll
            for (int mi = 0; mi < 8; ++mi)
#pragma unroll
                for (int ni = 0; ni < 4; ++ni)
                    acc[mi][ni] = __builtin_amdgcn_mfma_f32_16x16x32_bf16(
                        af[mi], bfr[ni], acc[mi][ni], 0, 0, 0);
            __builtin_amdgcn_s_setprio(0);
        }
    };

    uint2 c0k0, c0k1, c1k0, c1k1;
    float s0, s1;

    // prologue: tile 0 -> buf 0 (7 VMEM outstanding)
    stageA(0, 0);
    loadB(0, c0k0, c0k1, s0);

    for (int j = 0; j < NT / 2; ++j) {
        const int t1 = 2 * j + 1;
        // even tile 2j -> buf 0
        stageA(1, (2 * j + 1) * 64);
        loadB(t1, c1k0, c1k1, s1);       // +7 -> 14 outstanding
        WAITV(7);                        // tile 2j's window drained
        dqw(0, c0k0, c0k1, s0);
        LGKM0();
        BAR();                           // tile 2j fully visible
        compute(0);
        BAR();                           // all reads of buf0 done (WAR-safe)
        // odd tile 2j+1 -> buf 1
        if (j < NT / 2 - 1) {
            stageA(0, (t1 + 1) * 64);
            loadB(t1 + 1, c0k0, c0k1, s0);
            WAITV(7);
        } else {
            WAITV(0);
        }
        dqw(1, c1k0, c1k1, s1);
        LGKM0();
        BAR();
        compute(1);
        BAR();
    }

    // epilogue: C/D layout col=lane&15, row=(lane>>4)*4+r ; fp32 out
    const int crow = m0 + wm * 128 + kq * 4;
    const int ccol = n0 + wn * 64 + rl;
#pragma unroll
    for (int mi = 0; mi < 8; ++mi) {
#pragma unroll
        for (int r = 0; r < 4; ++r) {
            float* cp = C + (size_t)(crow + mi * 16 + r) * ND + ccol;
#pragma unroll
            for (int ni = 0; ni < 4; ++ni)
                cp[ni * 16] = acc[mi][ni][r];
        }
    }
}

extern "C" void kernel_launch(void* const* d_in, const int* in_sizes, int n_in,
                              void* d_out, int out_size, void* d_ws, size_t ws_size,
                              hipStream_t stream) {
    const float* x  = (const float*)d_in[0];
    const int*   wp = (const int*)d_in[1];
    const float* sc = (const float*)d_in[2];
    float* out = (float*)d_out;

    // ws layout: [0, PK): true-packed W (22.5 MB); rest: x as bf16 (m-chunked)
    const size_t PK = (size_t)ND * (KD / 2);   // packed bytes == wp int32 count
    if (ws_size <= PK + (size_t)256 * KD * 2) return;
    uint* wpk  = (uint*)d_ws;
    bf16* xbuf = (bf16*)((char*)d_ws + PK);

    long long rows_cap = (long long)((ws_size - PK) / ((size_t)KD * 2));
    int mc = (int)((rows_cap / 256) * 256);
    if (mc <= 0) return;
    if (mc > MD) mc = MD;

    const int n4 = (int)(PK / 4);              // uints of wpk (each eats 4 int32 of wp)
    repack_kernel<<<(n4 + 255) / 256, 256, 0, stream>>>(wp, wpk, n4);

    const int ntiles = ND / 256;  // 43
    for (int m0 = 0; m0 < MD; m0 += mc) {
        int mrows = (MD - m0 < mc) ? (MD - m0) : mc;   // multiple of 256
        int n8 = mrows * (KD / 8);
        cvt_kernel<<<(n8 + 255) / 256, 256, 0, stream>>>(x + (size_t)m0 * KD, xbuf, n8);
        int mt = mrows / 256;
        gemm256<<<mt * ntiles, 512, 0, stream>>>(xbuf, wpk, sc, out + (size_t)m0 * ND,
                                                 mt, ntiles);
    }
}

// Round 13
// 1642.905 us; speedup vs baseline: 1.3506x; 1.3506x over previous
//
#include <hip/hip_runtime.h>
#include <hip/hip_bf16.h>

#define KD 4096
#define ND 11008
#define MD 16384
#define KGD 32
#define NT (KD / 64)

typedef __hip_bfloat16 bf16;
typedef float f32x4 __attribute__((ext_vector_type(4)));
typedef short bf16x8 __attribute__((ext_vector_type(8)));

#define WAITV(n) asm volatile("s_waitcnt vmcnt(" #n ")" ::: "memory")
#define BAR()    asm volatile("s_barrier" ::: "memory")

__device__ __forceinline__ void gload16(const bf16* g, bf16* l) {
    __builtin_amdgcn_global_load_lds((const __attribute__((address_space(1))) void*)g,
                                     (__attribute__((address_space(3))) void*)l, 16, 0, 0);
}

// ---------------------------------------------------------------------------
// x: fp32 -> bf16 (8 elems/thread)
// ---------------------------------------------------------------------------
__global__ void cvt_kernel(const float* __restrict__ x, bf16* __restrict__ y, int n8) {
    int i = blockIdx.x * blockDim.x + threadIdx.x;
    if (i >= n8) return;
    const f32x4* p = reinterpret_cast<const f32x4*>(x + (size_t)i * 8);
    f32x4 a = p[0], b = p[1];
    bf16 o[8];
#pragma unroll
    for (int e = 0; e < 4; ++e) {
        o[e]     = __float2bfloat16(a[e]);
        o[4 + e] = __float2bfloat16(b[e]);
    }
    *reinterpret_cast<bf16x8*>(y + (size_t)i * 8) = *reinterpret_cast<bf16x8*>(o);
}

// ---------------------------------------------------------------------------
// dequant packed int4 -> bf16 rows [n0 .. n0+rows) into wd (chunk-local)
// ---------------------------------------------------------------------------
__global__ void dequant_kernel(const int* __restrict__ wp, const float* __restrict__ sc,
                               bf16* __restrict__ wd, int n0, int rows) {
    const int per_row = KD / 8;
    int t = blockIdx.x * blockDim.x + threadIdx.x;
    if (t >= rows * per_row) return;
    int lr = t / per_row;
    int q  = t - lr * per_row;
    int n  = n0 + lr;
    int j  = q * 4;
    const int4 p = *reinterpret_cast<const int4*>(wp + (size_t)n * (KD / 2) + j);
    float s = sc[(size_t)n * KGD + (j >> 6)];
    int v[4] = {p.x, p.y, p.z, p.w};
    bf16 o[8];
#pragma unroll
    for (int i = 0; i < 4; ++i) {
        o[2 * i]     = __float2bfloat16((float)((v[i] & 0xF) - 8) * s);
        o[2 * i + 1] = __float2bfloat16((float)(((v[i] >> 4) & 0xF) - 8) * s);
    }
    *reinterpret_cast<bf16x8*>(wd + (size_t)lr * KD + j * 2) = *reinterpret_cast<bf16x8*>(o);
}

// ---------------------------------------------------------------------------
// GEMM: C[M,N] = A[M,K] * B[N,K]^T, bf16 in, fp32 out.
// 256x256 tile, BK=64 (two kh=32), 512 thr / 8 waves (2M x 4N), per-wave
// out 128x64, mfma_f32_16x16x32_bf16, 128 KiB LDS double-buffered, proven
// conflict-free chunk swizzle via pre-swizzled global source.
// KEY CHANGE vs R5: compute() uses DISJOINT frag register sets for kh0/kh1
// (af0/bf0, af1/bf1). All 24 ds_reads issue before the first MFMA; the
// first MFMA waits only lgkmcnt(12) so kh1's reads stream down the LDS pipe
// while kh0's MFMAs retire on the matrix pipe — breaking the WAR-on-frag-reg
// serialization that forced serial LDS+MFMA (the 52%-MfmaUtil plateau).
// Ledger (R9, sound): stage(t+1) -> WAITV(8) -> BAR -> compute(t) -> BAR.
// ---------------------------------------------------------------------------
__global__ __launch_bounds__(512, 2) void gemm256(const bf16* __restrict__ A,
                                                  const bf16* __restrict__ B,
                                                  float* __restrict__ C,
                                                  int mtiles, int ntiles, int n0base) {
    __shared__ bf16 lds[2][2][2][8192];  // [buf][kh][op(A/B)][256 rows x 32 k, swizzled]
    const int tid  = threadIdx.x;
    const int lane = tid & 63;
    const int w    = tid >> 6;

    // bijective XCD-aware block swizzle
    int nwg = mtiles * ntiles;
    int orig = blockIdx.x;
    int q8 = nwg >> 3, r8 = nwg & 7;
    int xcd = orig & 7, off = orig >> 3;
    int wg = (xcd < r8 ? xcd * (q8 + 1) : r8 * (q8 + 1) + (xcd - r8) * q8) + off;
    const int mb = wg / ntiles, nb = wg - mb * ntiles;
    const int m0 = mb * 256, n0 = nb * 256;

    const int wm = w >> 2, wn = w & 3;
    const int rl = lane & 15, kq = lane >> 4;
    const int sz = (rl >> 1) & 3;
    const int ro = 8 * (kq ^ sz);          // swizzled k-chunk for ds_read

    // staging source (pre-swizzled so linear gload_lds dest == swizzled layout)
    const int src_c = (((lane & 3) ^ ((lane >> 3) & 3)) << 3);
    const int src_r = (w << 4) + (lane >> 2);
    const bf16* Abase = A + (size_t)(m0 + src_r) * KD + src_c;
    const bf16* Bbase = B + (size_t)(n0 + src_r) * KD + src_c;

    f32x4 acc[8][4] = {};

    auto stage = [&](int b, int kh, int k0) {
        const bf16* ga = Abase + k0 + kh * 32;
        const bf16* gb = Bbase + k0 + kh * 32;
        bf16* la = &lds[b][kh][0][w * 512];
        bf16* lb = &lds[b][kh][1][w * 512];
        gload16(ga, la);
        gload16(ga + (size_t)128 * KD, la + 4096);
        gload16(gb, lb);
        gload16(gb + (size_t)128 * KD, lb + 4096);
    };

    auto compute = [&](int b) {
        bf16x8 af0[8], bf0[4], af1[8], bf1[4];   // disjoint sets: kh0 / kh1
#pragma unroll
        for (int mi = 0; mi < 8; ++mi)
            af0[mi] = *reinterpret_cast<const bf16x8*>(
                &lds[b][0][0][(wm * 128 + mi * 16 + rl) * 32 + ro]);
#pragma unroll
        for (int ni = 0; ni < 4; ++ni)
            bf0[ni] = *reinterpret_cast<const bf16x8*>(
                &lds[b][0][1][(wn * 64 + ni * 16 + rl) * 32 + ro]);
#pragma unroll
        for (int mi = 0; mi < 8; ++mi)
            af1[mi] = *reinterpret_cast<const bf16x8*>(
                &lds[b][1][0][(wm * 128 + mi * 16 + rl) * 32 + ro]);
#pragma unroll
        for (int ni = 0; ni < 4; ++ni)
            bf1[ni] = *reinterpret_cast<const bf16x8*>(
                &lds[b][1][1][(wn * 64 + ni * 16 + rl) * 32 + ro]);
        __builtin_amdgcn_s_setprio(1);
#pragma unroll
        for (int mi = 0; mi < 8; ++mi)
#pragma unroll
            for (int ni = 0; ni < 4; ++ni)
                acc[mi][ni] = __builtin_amdgcn_mfma_f32_16x16x32_bf16(
                    af0[mi], bf0[ni], acc[mi][ni], 0, 0, 0);
#pragma unroll
        for (int mi = 0; mi < 8; ++mi)
#pragma unroll
            for (int ni = 0; ni < 4; ++ni)
                acc[mi][ni] = __builtin_amdgcn_mfma_f32_16x16x32_bf16(
                    af1[mi], bf1[ni], acc[mi][ni], 0, 0, 0);
        __builtin_amdgcn_s_setprio(0);
    };

    // prologue: tile 0 -> buf 0 (8 loads outstanding)
    stage(0, 0, 0);
    stage(0, 1, 0);

    for (int t = 0; t < NT - 1; ++t) {
        const int cur = t & 1, nxt = cur ^ 1, k0n = (t + 1) * 64;
        stage(nxt, 0, k0n);
        stage(nxt, 1, k0n);     // 16 outstanding
        WAITV(8);               // tile t fully landed (newest 8 = tile t+1)
        BAR();                  // all waves: tile t visible
        compute(cur);
        BAR();                  // all reads of buf[cur] done -> WAR-safe for t+2 stage
    }
    WAITV(0);
    BAR();
    compute((NT - 1) & 1);

    // epilogue: C/D layout col=lane&15, row=(lane>>4)*4+r ; fp32 out
    const int crow = m0 + wm * 128 + kq * 4;
    const int ccol = n0base + n0 + wn * 64 + rl;
#pragma unroll
    for (int mi = 0; mi < 8; ++mi) {
#pragma unroll
        for (int r = 0; r < 4; ++r) {
            float* cp = C + (size_t)(crow + mi * 16 + r) * ND + ccol;
#pragma unroll
            for (int ni = 0; ni < 4; ++ni)
                cp[ni * 16] = acc[mi][ni][r];
        }
    }
}

extern "C" void kernel_launch(void* const* d_in, const int* in_sizes, int n_in,
                              void* d_out, int out_size, void* d_ws, size_t ws_size,
                              hipStream_t stream) {
    const float* x  = (const float*)d_in[0];
    const int*   wp = (const int*)d_in[1];
    const float* sc = (const float*)d_in[2];
    float* out = (float*)d_out;

    // partition ws into x-bf16 chunk (mc rows) + W-bf16 chunk (nc rows), both x256
    long long rows_cap = (long long)(ws_size / ((size_t)KD * 2));
    int mc, nc;
    if (rows_cap >= MD + 256) {
        mc = MD;
        long long r = rows_cap - MD;
        nc = (int)((r / 256) * 256);
        if (nc > ND) nc = ND;
    } else if (rows_cap >= ND + 256) {
        nc = ND;
        long long r = rows_cap - ND;
        mc = (int)((r / 256) * 256);
        if (mc > MD) mc = MD;
    } else {
        nc = (int)(((rows_cap / 2) / 256) * 256);
        if (nc > ND) nc = ND;
        long long r = rows_cap - nc;
        mc = (int)((r / 256) * 256);
        if (mc > MD) mc = MD;
        if (mc <= 0 || nc <= 0) return;
    }

    bf16* xbuf = (bf16*)d_ws;
    bf16* wbuf = xbuf + (size_t)mc * KD;

    for (int m0 = 0; m0 < MD; m0 += mc) {
        int mrows = (MD - m0 < mc) ? (MD - m0) : mc;   // multiple of 256
        int n8 = mrows * (KD / 8);
        cvt_kernel<<<(n8 + 255) / 256, 256, 0, stream>>>(x + (size_t)m0 * KD, xbuf, n8);
        for (int n0 = 0; n0 < ND; n0 += nc) {
            int nrows = (ND - n0 < nc) ? (ND - n0) : nc;  // multiple of 256
            int tt = nrows * (KD / 8);
            dequant_kernel<<<(tt + 255) / 256, 256, 0, stream>>>(wp, sc, wbuf, n0, nrows);
            int mt = mrows / 256, nt2 = nrows / 256;
            gemm256<<<mt * nt2, 512, 0, stream>>>(xbuf, wbuf, out + (size_t)m0 * ND, mt, nt2, n0);
        }
    }
}